// Round 12
// baseline (9803.213 us; speedup 1.0000x reference)
//
#include <hip/hip_runtime.h>
#include <hip/hip_fp16.h>

#define B_ 256
#define S_ 512
#define F_ 64
#define H_ 1024
#define O_ 24
#define G_ 4096  // 4*H
#define NT_ 64   // ht' tile count (16-col tiles)

typedef _Float16 half_t;
typedef _Float16 h8 __attribute__((ext_vector_type(8)));
typedef float f4 __attribute__((ext_vector_type(4)));

// ---- workspace layout (bytes) ----
#define OFF_H1 ((size_t)0)                                   // 2*B*H halfs (ping-pong)
#define OFF_H2 (OFF_H1 + (size_t)2*B_*H_*2)
#define OFF_C1 (OFF_H2 + (size_t)2*B_*H_*2)                  // B*H f32
#define OFF_C2 (OFF_C1 + (size_t)B_*H_*4)
#define OFF_OP (OFF_C2 + (size_t)B_*H_*4)                    // out_part [64][B][O] f32
#define ZBYTES (OFF_OP + (size_t)NT_*B_*O_*4)
#define OFF_BIAS0 (ZBYTES)
#define OFF_BIAS1 (OFF_BIAS0 + (size_t)G_*4)
#define OFF_XH    (OFF_BIAS1 + (size_t)G_*4)                 // B*S*F halfs
#define OFF_WIH0  (OFF_XH + (size_t)B_*S_*F_*2)              // packed, G*F halfs
#define OFF_WHH0  (OFF_WIH0 + (size_t)G_*F_*2)               // packed, G*H halfs
#define OFF_WIH1  (OFF_WHH0 + (size_t)G_*H_*2)
#define OFF_WHH1  (OFF_WIH1 + (size_t)G_*H_*2)
#define WS_NEEDED (OFF_WHH1 + (size_t)G_*H_*2)               // ~46 MiB

__global__ void k_bias(const float* __restrict__ bi0, const float* __restrict__ bh0,
                       const float* __restrict__ bi1, const float* __restrict__ bh1,
                       float* __restrict__ bias0, float* __restrict__ bias1) {
    int i = blockIdx.x * blockDim.x + threadIdx.x;
    if (i < G_) { bias0[i] = bi0[i] + bh0[i]; bias1[i] = bi1[i] + bh1[i]; }
}

__global__ void k_cvt(const float* __restrict__ src, half_t* __restrict__ dst, int n) {
    int i = blockIdx.x * blockDim.x + threadIdx.x;
    int stride = gridDim.x * blockDim.x;
    for (; i < n; i += stride) dst[i] = (half_t)src[i];
}

// Pack W [4H, NC*64] f32 -> fp16 MFMA-fragment order:
// dst h8 index i = (((g*32+ht)*NC + ck)*4 + j)*64 + lane, j = colhalf*2 + kshalf
__global__ void k_pack(const float* __restrict__ src, half_t* __restrict__ dst, int NC) {
    int i = blockIdx.x * blockDim.x + threadIdx.x;
    int total = 32768 * NC;          // 4*32*NC*4*64
    if (i >= total) return;
    int lane = i & 63;
    int j    = (i >> 6) & 3;
    int ck   = (i >> 8) % NC;
    int gh   = i / (256 * NC);       // g*32+ht, 0..127
    int srow = (gh >> 5) * H_ + (gh & 31) * 32 + (j >> 1) * 16 + (lane & 15);
    int scol = ck * 64 + (j & 1) * 32 + (lane >> 4) * 8;
    const float* s = src + (size_t)srow * (NC * 64) + scol;
    h8 v;
    #pragma unroll
    for (int e = 0; e < 8; ++e) v[e] = (half_t)s[e];
    *(h8*)&dst[(size_t)i * 8] = v;
}

// ---------------------------------------------------------------------------
// R12 = R11 K-split wave dedup with the LDS slot-index bug FIXED:
// STEP's A-read offset was (BUFO + (coff+kh)*4608) -- for the buf1 steps
// (coff=4,6) that reads past the end of the 73728B A buffer (OOB garbage for
// every second half-window chunk -> absmax 0.15). Chunk c lives at slot c&3
// of its buffer, so: ao = BUFO + ((coff+kh)&3)*4608. Verified vs store side
// (chunk c -> buf(c&7<4?0:1) slot c&3); max read idx 36856 < 36864.
//
// Theory (R11): waves = (gate, K-parity) instead of (gate, row-half); each
// wave computes the FULL 64x16 gate tile over even-or-odd chunks -> every W
// fetch wave-unique -> per-CU W bytes halve (784->392 KB/phase, -33% total).
// Partials combined in LDS gate scatter (kh=0 writes incl. bias, kh=1 adds).
// 8-chunk/iter loop (R5-verified Q/P A-scheme, 2 barriers/8 chunks) keeps
// the 4-set W rotation compile-time. All else = R10 champion.
// ---------------------------------------------------------------------------

__device__ __forceinline__ void bar_lds() {
    // LDS-visibility barrier WITHOUT vmcnt drain (keeps global prefetches live)
    asm volatile("s_waitcnt lgkmcnt(0)" ::: "memory");
    __builtin_amdgcn_s_barrier();
}

__device__ __forceinline__ void run_part(
    const int thr, const int bt, const int htp,
    const int cx, const int nchunks,
    const half_t* __restrict__ xb, const int ldx,
    const half_t* __restrict__ hp,
    const half_t* __restrict__ Wih, const half_t* __restrict__ Whh,
    const float* __restrict__ bias,
    float* __restrict__ c, half_t* __restrict__ hn_out,
    const float* __restrict__ fcWt, float* __restrict__ out_part,
    half_t* A_s, float* gate_s, float* h_s, float* fcw_s,
    const bool do_fc)
{
    const int wave = thr >> 6, lane = thr & 63;
    const int gate = wave >> 1, kh = wave & 1;   // kh = K-parity (was row-half)
    const int quad = lane >> 4, l15 = lane & 15;
    const int ar = thr >> 3;             // A staging row 0..63
    const int ak = (thr & 7) * 8;        // A staging k-offset (halfs)
    const int ghW = gate * 32 + (htp >> 1);
    const int jo  = (htp & 1) * 2;       // fragment col-half select

    // bias only in the kh=0 partial (partials are summed in the scatter)
    float bv = (kh == 0) ? bias[gate * H_ + htp * 16 + l15] : 0.f;
    f4 acc0 = (f4){bv, bv, bv, bv};      // output rows  0..15
    f4 acc1 = acc0;                      // output rows 16..31
    f4 acc2 = acc0;                      // output rows 32..47
    f4 acc3 = acc0;                      // output rows 48..63

    auto loadA = [&](int ck) -> f4 {
        const half_t* Ab; int lda, k0;
        if (ck < cx) { Ab = xb; lda = ldx; k0 = ck * 64; }
        else         { Ab = hp; lda = H_;  k0 = (ck - cx) * 64; }
        return *(const f4*)&Ab[(size_t)(bt * 64 + ar) * lda + k0 + ak];
    };
    auto fetchW = [&](int ck, h8& r0, h8& r1) {
        const half_t* Wb; int ckk, NC;
        if (ck < cx) { Wb = Wih; ckk = ck;      NC = cx; }
        else         { Wb = Whh; ckk = ck - cx; NC = 16; }
        const half_t* base = Wb + ((size_t)(((ghW * NC) + ckk) * 4 + jo) * 64 + lane) * 8;
        r0 = *(const h8*)(base + 0 * 512);
        r1 = *(const h8*)(base + 1 * 512);
    };

    // ---- prologue: chunks 0..3 staged, 4..7 pending; own W chunks j=0,1,2
    //      (absolute kh, kh+2, kh+4) -> sets 0,1,2 ----
    h8 W0a,W0b, W1a,W1b, W2a,W2b, W3a,W3b;
    f4 p0, p1, p2, p3;   // chunks s+4..s+7 -> buf1 (mid-iter store)
    f4 q0, q1, q2, q3;   // chunks s+8..s+11 -> buf0 (end-iter store)
    f4 a0_ = loadA(0), a1_ = loadA(1), a2_ = loadA(2), a3_ = loadA(3);
    p0 = loadA(4); p1 = loadA(5); p2 = loadA(6); p3 = loadA(7);
    fetchW(kh,     W0a, W0b);
    fetchW(kh + 2, W1a, W1b);
    fetchW(kh + 4, W2a, W2b);

    // epilogue prefetches: sole-owner c slice; const fcW slice (HBM-cold).
    // bar_lds keeps these in flight across the whole K-loop.
    const int eb = thr >> 4, ecol = thr & 15;
    const size_t cbase = (size_t)(bt * 64 + eb) * H_ + htp * 16 + ecol;
    float cpre0 = c[cbase];
    float cpre1 = c[cbase + (size_t)32 * H_];
    float fpre = 0.f;
    if (do_fc && thr < 384)
        fpre = fcWt[(size_t)(thr >> 4) * (S_ * H_) + htp * 16 + (thr & 15)];

    *(f4*)&A_s[0 * 4608 + ar * 72 + ak] = a0_;
    *(f4*)&A_s[1 * 4608 + ar * 72 + ak] = a1_;
    *(f4*)&A_s[2 * 4608 + ar * 72 + ak] = a2_;
    *(f4*)&A_s[3 * 4608 + ar * 72 + ak] = a3_;
    bar_lds();   // chunks 0..3 visible in buf0

    // STEP: consume own chunk cc = s+coff+kh at buffer slot (coff+kh)&3
    // (store side: chunk c -> buf(c&7<4?0:1), slot c&3); fetch own chunk
    // cc+6 into the set consumed 3 own-steps ago. 8 ds_reads + 8 MFMAs.
    #define STEP(coff, BUFO, C0, C1, N0, N1)                                               \
    {   const int cc = s + (coff) + kh;                                                    \
        if (cc < nchunks) {                                                                \
            if (cc + 6 < nchunks) fetchW(cc + 6, N0, N1);                                  \
            const int ao = (BUFO) + (((coff) + kh) & 3) * 4608;                            \
            h8 a00 = *(const h8*)&A_s[ao + (0  + l15) * 72 + quad * 8];                    \
            h8 a10 = *(const h8*)&A_s[ao + (16 + l15) * 72 + quad * 8];                    \
            h8 a20 = *(const h8*)&A_s[ao + (32 + l15) * 72 + quad * 8];                    \
            h8 a30 = *(const h8*)&A_s[ao + (48 + l15) * 72 + quad * 8];                    \
            h8 a01 = *(const h8*)&A_s[ao + (0  + l15) * 72 + 32 + quad * 8];               \
            h8 a11 = *(const h8*)&A_s[ao + (16 + l15) * 72 + 32 + quad * 8];               \
            h8 a21 = *(const h8*)&A_s[ao + (32 + l15) * 72 + 32 + quad * 8];               \
            h8 a31 = *(const h8*)&A_s[ao + (48 + l15) * 72 + 32 + quad * 8];               \
            acc0 = __builtin_amdgcn_mfma_f32_16x16x32_f16(a00, C0, acc0, 0, 0, 0);         \
            acc1 = __builtin_amdgcn_mfma_f32_16x16x32_f16(a10, C0, acc1, 0, 0, 0);         \
            acc2 = __builtin_amdgcn_mfma_f32_16x16x32_f16(a20, C0, acc2, 0, 0, 0);         \
            acc3 = __builtin_amdgcn_mfma_f32_16x16x32_f16(a30, C0, acc3, 0, 0, 0);         \
            acc0 = __builtin_amdgcn_mfma_f32_16x16x32_f16(a01, C1, acc0, 0, 0, 0);         \
            acc1 = __builtin_amdgcn_mfma_f32_16x16x32_f16(a11, C1, acc1, 0, 0, 0);         \
            acc2 = __builtin_amdgcn_mfma_f32_16x16x32_f16(a21, C1, acc2, 0, 0, 0);         \
            acc3 = __builtin_amdgcn_mfma_f32_16x16x32_f16(a31, C1, acc3, 0, 0, 0);         \
        }                                                                                  \
    }

    for (int s = 0; s < nchunks; s += 8) {
        // next-iter buf0 chunks (stored end of this iter; ~1-iter latency cover)
        if (s + 8  < nchunks) q0 = loadA(s + 8);
        if (s + 9  < nchunks) q1 = loadA(s + 9);
        if (s + 10 < nchunks) q2 = loadA(s + 10);
        if (s + 11 < nchunks) q3 = loadA(s + 11);

        STEP(0, 0,     W0a,W0b, W3a,W3b)   // own j%4=0: consume set0, fetch set3
        STEP(2, 0,     W1a,W1b, W0a,W0b)   // set1, fetch set0

        // store p (chunks s+4..s+7) to buf1; old readers drained at the
        // PREVIOUS iteration's final barrier.
        if (s + 4 < nchunks) *(f4*)&A_s[18432 + 0 * 4608 + ar * 72 + ak] = p0;
        if (s + 5 < nchunks) *(f4*)&A_s[18432 + 1 * 4608 + ar * 72 + ak] = p1;
        if (s + 6 < nchunks) *(f4*)&A_s[18432 + 2 * 4608 + ar * 72 + ak] = p2;
        if (s + 7 < nchunks) *(f4*)&A_s[18432 + 3 * 4608 + ar * 72 + ak] = p3;

        // next-iter buf1 chunks (~1.25-iter latency cover)
        if (s + 12 < nchunks) p0 = loadA(s + 12);
        if (s + 13 < nchunks) p1 = loadA(s + 13);
        if (s + 14 < nchunks) p2 = loadA(s + 14);
        if (s + 15 < nchunks) p3 = loadA(s + 15);

        bar_lds();   // buf1 (chunks s+4..s+7) visible

        STEP(4, 18432, W2a,W2b, W1a,W1b)   // set2, fetch set1
        STEP(6, 18432, W3a,W3b, W2a,W2b)   // set3, fetch set2

        // store q (chunks s+8..s+11) to buf0; readers (STEP 0/2 this iter)
        // drained at the mid barrier.
        if (s + 8  < nchunks) *(f4*)&A_s[0 * 4608 + ar * 72 + ak] = q0;
        if (s + 9  < nchunks) *(f4*)&A_s[1 * 4608 + ar * 72 + ak] = q1;
        if (s + 10 < nchunks) *(f4*)&A_s[2 * 4608 + ar * 72 + ak] = q2;
        if (s + 11 < nchunks) *(f4*)&A_s[3 * 4608 + ar * 72 + ak] = q3;
        bar_lds();   // buf0 (chunks s+8..s+11) visible
    }
    #undef STEP

    // two-pass gate scatter: kh=0 writes its partial (incl. bias), kh=1 adds.
    // (C/D layout: col=lane&15, row=quad*4+reg; acc_r covers rows r*16..r*16+15)
    if (kh == 0) {
        #pragma unroll
        for (int r = 0; r < 4; ++r) {
            gate_s[gate * (64 * 17) + (0  + quad * 4 + r) * 17 + l15] = acc0[r];
            gate_s[gate * (64 * 17) + (16 + quad * 4 + r) * 17 + l15] = acc1[r];
            gate_s[gate * (64 * 17) + (32 + quad * 4 + r) * 17 + l15] = acc2[r];
            gate_s[gate * (64 * 17) + (48 + quad * 4 + r) * 17 + l15] = acc3[r];
        }
    }
    bar_lds();
    if (kh == 1) {
        #pragma unroll
        for (int r = 0; r < 4; ++r) {
            gate_s[gate * (64 * 17) + (0  + quad * 4 + r) * 17 + l15] += acc0[r];
            gate_s[gate * (64 * 17) + (16 + quad * 4 + r) * 17 + l15] += acc1[r];
            gate_s[gate * (64 * 17) + (32 + quad * 4 + r) * 17 + l15] += acc2[r];
            gate_s[gate * (64 * 17) + (48 + quad * 4 + r) * 17 + l15] += acc3[r];
        }
    }
    bar_lds();

    // cell update: 64x16 = 1024 (b,h) elems, 2/thread; c prefetched at start
    #pragma unroll
    for (int kk = 0; kk < 2; ++kk) {
        int b = eb + kk * 32;
        float gi = gate_s[0 * (64 * 17) + b * 17 + ecol];
        float gf = gate_s[1 * (64 * 17) + b * 17 + ecol];
        float gg = gate_s[2 * (64 * 17) + b * 17 + ecol];
        float go = gate_s[3 * (64 * 17) + b * 17 + ecol];
        float si = 1.f / (1.f + __expf(-gi));
        float sf = 1.f / (1.f + __expf(-gf));
        float so = 1.f / (1.f + __expf(-go));
        float tg = tanhf(gg);
        float cn = sf * (kk ? cpre1 : cpre0) + si * tg;
        size_t cidx = cbase + (size_t)kk * 32 * H_;
        c[cidx] = cn;
        float hnv = so * tanhf(cn);
        hn_out[cidx] = (half_t)hnv;
        if (do_fc) h_s[b * 17 + ecol] = hnv;
    }

    if (do_fc) {
        if (thr < 384) fcw_s[thr] = fpre;   // [24][16] staged from prefetch
        bar_lds();
        #pragma unroll
        for (int q = 0; q < 3; ++q) {
            int p = thr + q * 512;           // 0..1535 = 64b x 24o
            int o = p >> 6, bb = p & 63;
            float s2 = 0.f;
            #pragma unroll
            for (int j = 0; j < 16; ++j)
                s2 += h_s[bb * 17 + j] * fcw_s[o * 16 + j];
            out_part[(size_t)htp * (B_ * O_) + (bt * 64 + bb) * O_ + o] += s2;
        }
    }
    bar_lds();   // guard LDS reuse by the next part
}

__global__ __launch_bounds__(512, 2)
void k_phase(int t,
             const half_t* __restrict__ x_h,
             const half_t* __restrict__ Wih0, const half_t* __restrict__ Whh0,
             const float* __restrict__ bias0, float* __restrict__ c1g, half_t* __restrict__ h1buf,
             const half_t* __restrict__ Wih1, const half_t* __restrict__ Whh1,
             const float* __restrict__ bias1, float* __restrict__ c2g, half_t* __restrict__ h2buf,
             const float* __restrict__ fcW, float* __restrict__ out_part)
{
    // double-buffered A: 2 x [4][64*72] halfs = 73728 B (chunk c&7<4 -> buf0)
    // epilogue LDS unioned on top (23296 B used)
    __shared__ __align__(16) char smraw[73728];
    half_t* A_s    = (half_t*)smraw;
    float*  gate_s = (float*)smraw;                  // [4][64*17] = 17408 B
    float*  h_s    = (float*)(smraw + 17408);        // [64*17]    =  4352 B
    float*  fcw_s  = (float*)(smraw + 21760);        // [24*16]    =  1536 B

    const int n   = blockIdx.x;
    const int htp = (n & 7) + 8 * ((n >> 3) & 7);    // htp % 8 == n % 8 (XCD-resident W)
    const int bt  = (n >> 6) & 3;
    const int thr = threadIdx.x;

    if (t < S_) {       // layer-0 part: h1(t) from x(t), h1(t-1)
        const int tt = t;
        run_part(thr, bt, htp, /*cx=*/1, /*nchunks=*/17,
                 x_h + (size_t)tt * F_, S_ * F_,
                 h1buf + (size_t)((tt - 1) & 1) * B_ * H_,
                 Wih0, Whh0, bias0, c1g,
                 h1buf + (size_t)(tt & 1) * B_ * H_,
                 nullptr, nullptr,
                 A_s, gate_s, h_s, fcw_s, false);
    }
    if (t > 0) {        // layer-1 part: h2(t-1) from h1(t-1), h2(t-2); + FC tail
        const int tt = t - 1;
        run_part(thr, bt, htp, /*cx=*/16, /*nchunks=*/32,
                 h1buf + (size_t)(tt & 1) * B_ * H_, H_,
                 h2buf + (size_t)((tt - 1) & 1) * B_ * H_,
                 Wih1, Whh1, bias1, c2g,
                 h2buf + (size_t)(tt & 1) * B_ * H_,
                 fcW + (size_t)tt * H_, out_part,
                 A_s, gate_s, h_s, fcw_s, true);
    }
}

__global__ void k_final(const float* __restrict__ out_part, const float* __restrict__ fcb,
                        float* __restrict__ out) {
    int i = blockIdx.x * blockDim.x + threadIdx.x;
    if (i >= B_ * O_) return;
    int o = i % O_;
    float s = fcb[o];
    for (int tl = 0; tl < NT_; ++tl) s += out_part[(size_t)tl * (B_ * O_) + i];
    out[i] = s;
}

extern "C" void kernel_launch(void* const* d_in, const int* in_sizes, int n_in,
                              void* d_out, int out_size, void* d_ws, size_t ws_size,
                              hipStream_t stream) {
    const float* x    = (const float*)d_in[0];
    const float* Wih0 = (const float*)d_in[1];
    const float* Whh0 = (const float*)d_in[2];
    const float* bih0 = (const float*)d_in[3];
    const float* bhh0 = (const float*)d_in[4];
    const float* Wih1 = (const float*)d_in[5];
    const float* Whh1 = (const float*)d_in[6];
    const float* bih1 = (const float*)d_in[7];
    const float* bhh1 = (const float*)d_in[8];
    const float* fcW  = (const float*)d_in[9];
    const float* fcb  = (const float*)d_in[10];

    char* ws = (char*)d_ws;
    half_t* h1buf  = (half_t*)(ws + OFF_H1);
    half_t* h2buf  = (half_t*)(ws + OFF_H2);
    float*  c1     = (float*)(ws + OFF_C1);
    float*  c2     = (float*)(ws + OFF_C2);
    float*  opart  = (float*)(ws + OFF_OP);
    float*  bias0  = (float*)(ws + OFF_BIAS0);
    float*  bias1  = (float*)(ws + OFF_BIAS1);
    half_t* x_h    = (half_t*)(ws + OFF_XH);
    half_t* wih0_p = (half_t*)(ws + OFF_WIH0);
    half_t* whh0_p = (half_t*)(ws + OFF_WHH0);
    half_t* wih1_p = (half_t*)(ws + OFF_WIH1);
    half_t* whh1_p = (half_t*)(ws + OFF_WHH1);

    // zero states + FC partials (ws poisoned 0xAA before every launch)
    hipMemsetAsync(d_ws, 0, ZBYTES, stream);

    k_bias<<<dim3((G_ + 255) / 256), dim3(256), 0, stream>>>(bih0, bhh0, bih1, bhh1, bias0, bias1);
    k_cvt<<<dim3(2048), dim3(256), 0, stream>>>(x, x_h, B_ * S_ * F_);
    k_pack<<<dim3(128),  dim3(256), 0, stream>>>(Wih0, wih0_p, 1);
    k_pack<<<dim3(2048), dim3(256), 0, stream>>>(Whh0, whh0_p, 16);
    k_pack<<<dim3(2048), dim3(256), 0, stream>>>(Wih1, wih1_p, 16);
    k_pack<<<dim3(2048), dim3(256), 0, stream>>>(Whh1, whh1_p, 16);

    dim3 grid(256), blk(512);
    for (int t = 0; t <= S_; ++t) {
        k_phase<<<grid, blk, 0, stream>>>(t, x_h,
                                          wih0_p, whh0_p, bias0, c1, h1buf,
                                          wih1_p, whh1_p, bias1, c2, h2buf,
                                          fcW, opart);
    }
    k_final<<<dim3((B_ * O_ + 255) / 256), dim3(256), 0, stream>>>(opart, fcb, (float*)d_out);
}